// Round 4
// baseline (210.867 us; speedup 1.0000x reference)
//
#include <hip/hip_runtime.h>
#include <cstdint>

#define B 16
#define H 128
#define W 128
#define NC 80
#define PB (H*W*NC)
#define K 100
#define CAP 16384
#define THRESH 0.95f
#define NBINS 4096
#define LISTCAP 512
#define TY 8             // output rows per wave-tile
#define OX 14            // output cols per wave-tile (16 loaded, 14 emitted)
#define YT (H/TY)        // 16
#define XT ((W + OX - 1)/OX)   // 10

__device__ unsigned long long g_cand[B * CAP];
__device__ int g_counts[B * 16] = {};   // zeroed at load; topk re-zeros after use

__device__ __forceinline__ float sigmoidf(float x) {
    return 1.0f / (1.0f + expf(-x));
}
__device__ __forceinline__ float4 f4max2(float4 a, float4 b) {
    float4 r;
    r.x = fmaxf(a.x, b.x); r.y = fmaxf(a.y, b.y);
    r.z = fmaxf(a.z, b.z); r.w = fmaxf(a.w, b.w);
    return r;
}
__device__ __forceinline__ float4 shfl4(float4 v, int src) {
    float4 r;
    r.x = __shfl(v.x, src);
    r.y = __shfl(v.y, src);
    r.z = __shfl(v.z, src);
    r.w = __shfl(v.w, src);
    return r;
}

// Stage A: fused sigmoid + 3x3 peak NMS + compaction.
// One wave per (b, 8-row y-tile, 14-col overlapped x-tile, 16-class group).
// All 10 rows preloaded (MLP=10, monotone vmcnt drain). No LDS, no barriers,
// no edge loads: wave loads 16 cols (incl. halo), emits middle 14.
// 3x3 max = vertical max in registers, then one horizontal pass via shuffles.
__global__ __launch_bounds__(320) void peak_kernel(const float* __restrict__ cls) {
    const int blk = blockIdx.x;                  // 16*16*10 = 2560
    const int b   = blk / (YT * XT);
    const int rem = blk - b * (YT * XT);
    const int yt  = rem / XT;
    const int xt  = rem - yt * XT;
    const int lane = threadIdx.x & 63;
    const int cg   = threadIdx.x >> 6;           // class group 0..4
    const int c4   = lane & 3;
    const int xl   = lane >> 2;                  // 0..15
    const int xg   = xt * OX - 1 + xl;           // global col (may be OOB)
    const int y0   = yt * TY;
    const int cbase = cg * 16 + c4 * 4;

    const float NI = -__builtin_inff();
    const float4 NEG = make_float4(NI, NI, NI, NI);
    const float* bp = cls + (size_t)b * PB;

    const bool xv = (xg >= 0) & (xg < W);
    const bool emitOK = (xl >= 1) & (xl <= OX) & (xg < W);   // xg>=0 implied

    // preload all 10 rows -> 10 loads in flight per wave
    float4 r[TY + 2];
    #pragma unroll
    for (int j = 0; j < TY + 2; ++j) {
        const int y = y0 - 1 + j;
        const bool ok = (y >= 0) & (y < H) & xv;
        r[j] = ok ? *(const float4*)(bp + ((size_t)(y * W + xg)) * NC + cbase) : NEG;
    }

    const int lsrcL = (lane - 4) & 63;
    const int lsrcR = (lane + 4) & 63;

    float4 pairA = f4max2(r[0], r[1]);           // max of rows k, k+1
    #pragma unroll
    for (int k = 0; k < TY; ++k) {
        float4 vert = f4max2(pairA, r[k + 2]);   // vertical 3-max at own column
        float4 L = shfl4(vert, lsrcL);
        float4 R = shfl4(vert, lsrcR);
        float4 vm4 = f4max2(f4max2(L, R), vert); // full 3x3 max (logit space)
        float4 vc4 = r[k + 1];                   // center value

        if (emitOK) {
            const int yo = y0 + k;
            float vv[4] = { vc4.x, vc4.y, vc4.z, vc4.w };
            float mm[4] = { vm4.x, vm4.y, vm4.z, vm4.w };
            #pragma unroll
            for (int c = 0; c < 4; ++c) {
                float v = vv[c], vm = mm[c];
                // logit prefilter: sigmoid(2.9)<0.95; 1e-3 band >> worst-case
                // sigmoid rounding-collision window (~1.5e-5)
                if (v > 2.9f && (vm - v) <= 1e-3f) {
                    float sc = sigmoidf(v);
                    float sm = sigmoidf(vm);     // = max(sigmoid(window)), monotone
                    if (sc == sm && sc > THRESH) {
                        unsigned ib = ((unsigned)(yo * W + xg)) * NC + cbase + c;
                        unsigned long long key =
                            ((unsigned long long)__float_as_uint(sc) << 32) |
                            (unsigned long long)(0xFFFFFFFFu - ib);
                        int slot = atomicAdd(&g_counts[b * 16], 1);
                        if (slot < CAP) g_cand[b * CAP + slot] = key;
                    }
                }
            }
        }
        pairA = f4max2(r[k + 1], r[k + 2]);
    }
}

// Stage B: per-batch exact top-K (histogram cutoff -> collect -> rank-by-count -> decode)
__global__ __launch_bounds__(256) void topk_kernel(const float* __restrict__ dxy,
                                                   const float* __restrict__ swh,
                                                   float* __restrict__ out) {
    const int b = blockIdx.x;
    const int tid = threadIdx.x;
    __shared__ int hist[NBINS];
    __shared__ int csum[256];
    __shared__ unsigned long long list[LISTCAP];
    __shared__ int lcount;
    __shared__ int kstar;

    int n = g_counts[b * 16];
    if (n > CAP) n = CAP;
    const unsigned long long* cb = g_cand + (size_t)b * CAP;

    for (int i = tid; i < NBINS; i += 256) hist[i] = 0;
    if (tid == 0) lcount = 0;
    __syncthreads();

    const float SCALE = (float)NBINS / (1.0f - THRESH);
    for (int i = tid; i < n; i += 256) {
        float v = __uint_as_float((unsigned)(cb[i] >> 32));
        int bin = (int)((v - THRESH) * SCALE);
        bin = bin < 0 ? 0 : (bin > NBINS - 1 ? NBINS - 1 : bin);
        atomicAdd(&hist[bin], 1);
    }
    __syncthreads();

    int s = 0;
    for (int j = 0; j < NBINS / 256; j++) s += hist[tid * (NBINS / 256) + j];
    csum[tid] = s;
    __syncthreads();

    if (tid == 0) {
        int acc = 0;
        int chunk = 255;
        for (; chunk >= 0; chunk--) {
            if (acc + csum[chunk] >= K) break;
            acc += csum[chunk];
        }
        int ks = 0;
        if (chunk >= 0) {
            int j = NBINS / 256 - 1;
            for (; j >= 0; j--) {
                acc += hist[chunk * (NBINS / 256) + j];
                if (acc >= K) break;
            }
            if (j < 0) j = 0;
            ks = chunk * (NBINS / 256) + j;
        }
        kstar = ks;
    }
    __syncthreads();

    const int ks = kstar;
    for (int i = tid; i < n; i += 256) {
        unsigned long long key = cb[i];
        float v = __uint_as_float((unsigned)(key >> 32));
        int bin = (int)((v - THRESH) * SCALE);
        bin = bin < 0 ? 0 : (bin > NBINS - 1 ? NBINS - 1 : bin);
        if (bin >= ks) {
            int p = atomicAdd(&lcount, 1);
            if (p < LISTCAP) list[p] = key;
        }
    }
    __syncthreads();
    const int M = lcount < LISTCAP ? lcount : LISTCAP;

    // exact rank by counting (keys distinct: low 32 bits unique per batch)
    for (int i = tid; i < M; i += 256) {
        unsigned long long key = list[i];
        int rank = 0;
        for (int j = 0; j < M; j++) rank += (list[j] > key);
        if (rank < K) {
            float conf = __uint_as_float((unsigned)(key >> 32));
            unsigned ib = 0xFFFFFFFFu - (unsigned)(key & 0xFFFFFFFFu);
            unsigned cls_i = ib % (unsigned)NC;
            unsigned sidx = ib / (unsigned)NC;
            unsigned xg = sidx & (W - 1);
            unsigned yg = sidx >> 7;

            size_t goff = ((size_t)b * (H * W) + sidx) * 2;
            float dx = dxy[goff], dy = dxy[goff + 1];
            float sw = swh[goff], sh = swh[goff + 1];

            float xs = (float)xg + dx;
            float ys = (float)yg + dy;
            float hw = sw * 0.5f;
            float hh = sh * 0.5f;
            const float invW = 1.0f / (float)W;
            const float invH = 1.0f / (float)H;

            int r = b * K + rank;
            out[r * 4 + 0] = (xs - hw) * invW;
            out[r * 4 + 1] = (ys - hh) * invH;
            out[r * 4 + 2] = (xs + hw) * invW;
            out[r * 4 + 3] = (ys + hh) * invH;
            out[B * K * 4 + r] = conf;
            out[B * K * 4 + B * K + r] = (float)cls_i;
        }
    }

    __syncthreads();
    if (tid == 0) g_counts[b * 16] = 0;   // reset for next call (single writer)
}

extern "C" void kernel_launch(void* const* d_in, const int* in_sizes, int n_in,
                              void* d_out, int out_size, void* d_ws, size_t ws_size,
                              hipStream_t stream) {
    const float* cls = (const float*)d_in[0];
    const float* dxy = (const float*)d_in[1];
    const float* swh = (const float*)d_in[2];
    float* out = (float*)d_out;

    peak_kernel<<<B * YT * XT, 320, 0, stream>>>(cls);
    topk_kernel<<<B, 256, 0, stream>>>(dxy, swh, out);
}

// Round 5
// 176.846 us; speedup vs baseline: 1.1924x; 1.1924x over previous
//
#include <hip/hip_runtime.h>
#include <cstdint>

#define B 16
#define H 128
#define W 128
#define NC 80
#define PB (H*W*NC)
#define K 100
#define CAP 16384
#define THRESH 0.95f
#define NBINS 4096
#define LISTCAP 512
#define TY 16            // output rows per wave-tile
#define OX 14            // output cols per wave-tile (16 loaded, 14 emitted)
#define YT (H/TY)        // 8
#define XT 10            // ceil(W/OX)

__device__ unsigned long long g_cand[B * CAP];
__device__ int g_counts[B * 16] = {};   // zeroed at load; topk re-zeros after use

__device__ __forceinline__ float sigmoidf(float x) {
    return 1.0f / (1.0f + expf(-x));
}
__device__ __forceinline__ float4 f4max2(float4 a, float4 b) {
    float4 r;
    r.x = fmaxf(a.x, b.x); r.y = fmaxf(a.y, b.y);
    r.z = fmaxf(a.z, b.z); r.w = fmaxf(a.w, b.w);
    return r;
}
__device__ __forceinline__ float4 shfl4(float4 v, int src) {
    float4 r;
    r.x = __shfl(v.x, src);
    r.y = __shfl(v.y, src);
    r.z = __shfl(v.z, src);
    r.w = __shfl(v.w, src);
    return r;
}

// Stage A: fused sigmoid + 3x3 peak NMS + compaction.
// One wave per (b, 16-row y-tile, 14-col overlapped x-tile, 16-class group).
// No LDS/barriers; no edge loads (16 cols loaded, middle 14 emitted).
// Depth-4 load pipeline via NAMED registers ra..rd (round-4's r[10] array
// spilled to scratch: VGPR=32, WRITE_SIZE 2x -- never use arrays here).
__global__ __launch_bounds__(320) void peak_kernel(const float* __restrict__ cls) {
    const int blk = blockIdx.x;                  // B*YT*XT = 1280
    const int b   = blk / (YT * XT);
    const int rem = blk - b * (YT * XT);
    const int yt  = rem / XT;
    const int xt  = rem - yt * XT;
    const int lane = threadIdx.x & 63;
    const int cg   = threadIdx.x >> 6;           // class group 0..4
    const int c4   = lane & 3;
    const int xl   = lane >> 2;                  // 0..15
    const int xg   = xt * OX - 1 + xl;           // global col, may be OOB
    const int y0   = yt * TY;
    const int cbase = cg * 16 + c4 * 4;

    const float NI = -__builtin_inff();
    const float4 NEG = make_float4(NI, NI, NI, NI);
    const float* bp = cls + (size_t)b * PB + cbase;

    const bool xv = (xg >= 0) & (xg < W);
    const bool emitOK = (xl >= 1) & (xl <= OX) & (xg < W);

    const int lsrcL = (lane - 4) & 63;
    const int lsrcR = (lane + 4) & 63;

    auto ld = [&](int j) -> float4 {             // raw row j  (y = y0-1+j)
        const int y = y0 - 1 + j;
        const bool ok = (y >= 0) & (y < H) & xv;
        return ok ? *(const float4*)(bp + (size_t)(y * W + xg) * NC) : NEG;
    };

    float4 ra = ld(0), rb = ld(1), rc = ld(2), rd = ld(3);   // 4 loads in flight
    float4 hm_prev = NEG, hm_curr = NEG, vprev = NEG;

    auto step = [&](float4& cur, int j) {        // j is a literal at every call
        float4 L = shfl4(cur, lsrcL);
        float4 R = shfl4(cur, lsrcR);
        float4 hm_next = f4max2(f4max2(L, R), cur);

        if (j >= 2 && emitOK) {
            const int yo = y0 + j - 2;           // output row (center = row j-1)
            float4 vm4 = f4max2(f4max2(hm_prev, hm_curr), hm_next);
            float vv[4] = { vprev.x, vprev.y, vprev.z, vprev.w };
            float mm[4] = { vm4.x, vm4.y, vm4.z, vm4.w };
            #pragma unroll
            for (int c = 0; c < 4; ++c) {
                float v = vv[c], vm = mm[c];
                // logit prefilter: sigmoid(2.9)<0.95; 1e-3 band >> worst-case
                // sigmoid rounding-collision window (~1.5e-5)
                if (v > 2.9f && (vm - v) <= 1e-3f) {
                    float sc = sigmoidf(v);
                    float sm = sigmoidf(vm);     // = max(sigmoid(window)), monotone
                    if (sc == sm && sc > THRESH) {
                        unsigned ib = ((unsigned)(yo * W + xg)) * NC + cbase + c;
                        unsigned long long key =
                            ((unsigned long long)__float_as_uint(sc) << 32) |
                            (unsigned long long)(0xFFFFFFFFu - ib);
                        int slot = atomicAdd(&g_counts[b * 16], 1);
                        if (slot < CAP) g_cand[b * CAP + slot] = key;
                    }
                }
            }
        }
        hm_prev = hm_curr; hm_curr = hm_next; vprev = cur;
        if (j + 4 <= TY + 1) cur = ld(j + 4);    // refill freed register
    };

    // 18 rows (TY+2), hand-unrolled 4-deep rotation: ra,rb,rc,rd,ra,...
    step(ra, 0);  step(rb, 1);  step(rc, 2);  step(rd, 3);
    step(ra, 4);  step(rb, 5);  step(rc, 6);  step(rd, 7);
    step(ra, 8);  step(rb, 9);  step(rc, 10); step(rd, 11);
    step(ra, 12); step(rb, 13); step(rc, 14); step(rd, 15);
    step(ra, 16); step(rb, 17);
}

// Stage B: per-batch exact top-K (histogram cutoff -> collect -> rank-by-count -> decode)
__global__ __launch_bounds__(256) void topk_kernel(const float* __restrict__ dxy,
                                                   const float* __restrict__ swh,
                                                   float* __restrict__ out) {
    const int b = blockIdx.x;
    const int tid = threadIdx.x;
    __shared__ int hist[NBINS];
    __shared__ int csum[256];
    __shared__ unsigned long long list[LISTCAP];
    __shared__ int lcount;
    __shared__ int kstar;

    int n = g_counts[b * 16];
    if (n > CAP) n = CAP;
    const unsigned long long* cb = g_cand + (size_t)b * CAP;

    for (int i = tid; i < NBINS; i += 256) hist[i] = 0;
    if (tid == 0) lcount = 0;
    __syncthreads();

    const float SCALE = (float)NBINS / (1.0f - THRESH);
    for (int i = tid; i < n; i += 256) {
        float v = __uint_as_float((unsigned)(cb[i] >> 32));
        int bin = (int)((v - THRESH) * SCALE);
        bin = bin < 0 ? 0 : (bin > NBINS - 1 ? NBINS - 1 : bin);
        atomicAdd(&hist[bin], 1);
    }
    __syncthreads();

    int s = 0;
    for (int j = 0; j < NBINS / 256; j++) s += hist[tid * (NBINS / 256) + j];
    csum[tid] = s;
    __syncthreads();

    if (tid == 0) {
        int acc = 0;
        int chunk = 255;
        for (; chunk >= 0; chunk--) {
            if (acc + csum[chunk] >= K) break;
            acc += csum[chunk];
        }
        int ks = 0;
        if (chunk >= 0) {
            int j = NBINS / 256 - 1;
            for (; j >= 0; j--) {
                acc += hist[chunk * (NBINS / 256) + j];
                if (acc >= K) break;
            }
            if (j < 0) j = 0;
            ks = chunk * (NBINS / 256) + j;
        }
        kstar = ks;
    }
    __syncthreads();

    const int ks = kstar;
    for (int i = tid; i < n; i += 256) {
        unsigned long long key = cb[i];
        float v = __uint_as_float((unsigned)(key >> 32));
        int bin = (int)((v - THRESH) * SCALE);
        bin = bin < 0 ? 0 : (bin > NBINS - 1 ? NBINS - 1 : bin);
        if (bin >= ks) {
            int p = atomicAdd(&lcount, 1);
            if (p < LISTCAP) list[p] = key;
        }
    }
    __syncthreads();
    const int M = lcount < LISTCAP ? lcount : LISTCAP;

    // exact rank by counting (keys distinct: low 32 bits unique per batch)
    for (int i = tid; i < M; i += 256) {
        unsigned long long key = list[i];
        int rank = 0;
        for (int j = 0; j < M; j++) rank += (list[j] > key);
        if (rank < K) {
            float conf = __uint_as_float((unsigned)(key >> 32));
            unsigned ib = 0xFFFFFFFFu - (unsigned)(key & 0xFFFFFFFFu);
            unsigned cls_i = ib % (unsigned)NC;
            unsigned sidx = ib / (unsigned)NC;
            unsigned xg = sidx & (W - 1);
            unsigned yg = sidx >> 7;

            size_t goff = ((size_t)b * (H * W) + sidx) * 2;
            float dx = dxy[goff], dy = dxy[goff + 1];
            float sw = swh[goff], sh = swh[goff + 1];

            float xs = (float)xg + dx;
            float ys = (float)yg + dy;
            float hw = sw * 0.5f;
            float hh = sh * 0.5f;
            const float invW = 1.0f / (float)W;
            const float invH = 1.0f / (float)H;

            int r = b * K + rank;
            out[r * 4 + 0] = (xs - hw) * invW;
            out[r * 4 + 1] = (ys - hh) * invH;
            out[r * 4 + 2] = (xs + hw) * invW;
            out[r * 4 + 3] = (ys + hh) * invH;
            out[B * K * 4 + r] = conf;
            out[B * K * 4 + B * K + r] = (float)cls_i;
        }
    }

    __syncthreads();
    if (tid == 0) g_counts[b * 16] = 0;   // reset for next call (single writer)
}

extern "C" void kernel_launch(void* const* d_in, const int* in_sizes, int n_in,
                              void* d_out, int out_size, void* d_ws, size_t ws_size,
                              hipStream_t stream) {
    const float* cls = (const float*)d_in[0];
    const float* dxy = (const float*)d_in[1];
    const float* swh = (const float*)d_in[2];
    float* out = (float*)d_out;

    peak_kernel<<<B * YT * XT, 320, 0, stream>>>(cls);
    topk_kernel<<<B, 256, 0, stream>>>(dxy, swh, out);
}

// Round 6
// 156.982 us; speedup vs baseline: 1.3433x; 1.1265x over previous
//
#include <hip/hip_runtime.h>
#include <cstdint>

#define B 16
#define H 128
#define W 128
#define NC 80
#define PB (H*W*NC)
#define K 100
#define NSUB 16          // sub-counters per batch (atomic distribution)
#define SEGCAP 1024      // candidate slots per (batch, sub)
#define THRESH 0.95f
#define NBINS 4096
#define LISTCAP 512
#define TY 16            // output rows per wave-tile
#define OX 14            // output cols per wave-tile (16 loaded, 14 emitted)
#define YT (H/TY)        // 8
#define XT 10            // ceil(W/OX)

__device__ unsigned long long g_cand[B * NSUB * SEGCAP];   // 2 MB
__device__ int g_counts[B * NSUB * 16] = {};  // 64B-strided; zeroed at load; topk re-zeros

__device__ __forceinline__ float sigmoidf(float x) {
    return 1.0f / (1.0f + expf(-x));
}
__device__ __forceinline__ float4 f4max2(float4 a, float4 b) {
    float4 r;
    r.x = fmaxf(a.x, b.x); r.y = fmaxf(a.y, b.y);
    r.z = fmaxf(a.z, b.z); r.w = fmaxf(a.w, b.w);
    return r;
}
__device__ __forceinline__ float4 shfl4(float4 v, int src) {
    float4 r;
    r.x = __shfl(v.x, src);
    r.y = __shfl(v.y, src);
    r.z = __shfl(v.z, src);
    r.w = __shfl(v.w, src);
    return r;
}

// Stage A: fused sigmoid + 3x3 peak NMS + compaction.
// One wave per (b, 16-row y-tile, 14-col overlapped x-tile, 16-class group).
// No LDS/barriers; no edge loads (16 cols loaded, middle 14 emitted).
// Atomic contention fix (round 6): per-(batch, block%16) sub-counters 64B
// apart, each owning a SEGCAP segment — kills the ~2100-deep same-address
// device-atomic chain that pinned rounds 3-5 at 55 us regardless of memory
// temperature or pipeline structure.
__global__ __launch_bounds__(320) void peak_kernel(const float* __restrict__ cls) {
    const int blk = blockIdx.x;                  // B*YT*XT = 1280
    const int b   = blk / (YT * XT);
    const int rem = blk - b * (YT * XT);
    const int yt  = rem / XT;
    const int xt  = rem - yt * XT;
    const int sub = rem & (NSUB - 1);            // 16-way atomic distribution
    const int lane = threadIdx.x & 63;
    const int cg   = threadIdx.x >> 6;           // class group 0..4
    const int c4   = lane & 3;
    const int xl   = lane >> 2;                  // 0..15
    const int xg   = xt * OX - 1 + xl;           // global col, may be OOB
    const int y0   = yt * TY;
    const int cbase = cg * 16 + c4 * 4;

    int* const cnt_p = &g_counts[(b * NSUB + sub) * 16];
    unsigned long long* const seg_p = &g_cand[(size_t)(b * NSUB + sub) * SEGCAP];

    const float NI = -__builtin_inff();
    const float4 NEG = make_float4(NI, NI, NI, NI);
    const float* bp = cls + (size_t)b * PB + cbase;

    const bool xv = (xg >= 0) & (xg < W);
    const bool emitOK = (xl >= 1) & (xl <= OX) & (xg < W);

    const int lsrcL = (lane - 4) & 63;
    const int lsrcR = (lane + 4) & 63;

    auto ld = [&](int j) -> float4 {             // raw row j  (y = y0-1+j)
        const int y = y0 - 1 + j;
        const bool ok = (y >= 0) & (y < H) & xv;
        return ok ? *(const float4*)(bp + (size_t)(y * W + xg) * NC) : NEG;
    };

    float4 ra = ld(0), rb = ld(1), rc = ld(2), rd = ld(3);   // 4 loads in flight
    float4 hm_prev = NEG, hm_curr = NEG, vprev = NEG;

    auto step = [&](float4& cur, int j) {        // j is a literal at every call
        float4 L = shfl4(cur, lsrcL);
        float4 R = shfl4(cur, lsrcR);
        float4 hm_next = f4max2(f4max2(L, R), cur);

        if (j >= 2 && emitOK) {
            const int yo = y0 + j - 2;           // output row (center = row j-1)
            float4 vm4 = f4max2(f4max2(hm_prev, hm_curr), hm_next);
            float vv[4] = { vprev.x, vprev.y, vprev.z, vprev.w };
            float mm[4] = { vm4.x, vm4.y, vm4.z, vm4.w };
            #pragma unroll
            for (int c = 0; c < 4; ++c) {
                float v = vv[c], vm = mm[c];
                // logit prefilter: sigmoid(2.9)<0.95; 1e-3 band >> worst-case
                // sigmoid rounding-collision window (~1.5e-5)
                if (v > 2.9f && (vm - v) <= 1e-3f) {
                    float sc = sigmoidf(v);
                    float sm = sigmoidf(vm);     // = max(sigmoid(window)), monotone
                    if (sc == sm && sc > THRESH) {
                        unsigned ib = ((unsigned)(yo * W + xg)) * NC + cbase + c;
                        unsigned long long key =
                            ((unsigned long long)__float_as_uint(sc) << 32) |
                            (unsigned long long)(0xFFFFFFFFu - ib);
                        int slot = atomicAdd(cnt_p, 1);
                        if (slot < SEGCAP) seg_p[slot] = key;
                    }
                }
            }
        }
        hm_prev = hm_curr; hm_curr = hm_next; vprev = cur;
        if (j + 4 <= TY + 1) cur = ld(j + 4);    // refill freed register
    };

    // 18 rows (TY+2), hand-unrolled 4-deep rotation: ra,rb,rc,rd,ra,...
    step(ra, 0);  step(rb, 1);  step(rc, 2);  step(rd, 3);
    step(ra, 4);  step(rb, 5);  step(rc, 6);  step(rd, 7);
    step(ra, 8);  step(rb, 9);  step(rc, 10); step(rd, 11);
    step(ra, 12); step(rb, 13); step(rc, 14); step(rd, 15);
    step(ra, 16); step(rb, 17);
}

// Stage B: per-batch exact top-K over 16 segments
// (histogram cutoff -> collect -> rank-by-count -> decode)
__global__ __launch_bounds__(256) void topk_kernel(const float* __restrict__ dxy,
                                                   const float* __restrict__ swh,
                                                   float* __restrict__ out) {
    const int b = blockIdx.x;
    const int tid = threadIdx.x;
    __shared__ int hist[NBINS];
    __shared__ int csum[256];
    __shared__ int segn[NSUB];
    __shared__ unsigned long long list[LISTCAP];
    __shared__ int lcount;
    __shared__ int kstar;

    if (tid < NSUB) {
        int n = g_counts[(b * NSUB + tid) * 16];
        segn[tid] = n > SEGCAP ? SEGCAP : n;
    }
    for (int i = tid; i < NBINS; i += 256) hist[i] = 0;
    if (tid == 0) lcount = 0;
    __syncthreads();

    const float SCALE = (float)NBINS / (1.0f - THRESH);
    #pragma unroll 1
    for (int s = 0; s < NSUB; ++s) {
        const unsigned long long* cb = g_cand + (size_t)(b * NSUB + s) * SEGCAP;
        const int n = segn[s];
        for (int i = tid; i < n; i += 256) {
            float v = __uint_as_float((unsigned)(cb[i] >> 32));
            int bin = (int)((v - THRESH) * SCALE);
            bin = bin < 0 ? 0 : (bin > NBINS - 1 ? NBINS - 1 : bin);
            atomicAdd(&hist[bin], 1);
        }
    }
    __syncthreads();

    int s0 = 0;
    for (int j = 0; j < NBINS / 256; j++) s0 += hist[tid * (NBINS / 256) + j];
    csum[tid] = s0;
    __syncthreads();

    if (tid == 0) {
        int acc = 0;
        int chunk = 255;
        for (; chunk >= 0; chunk--) {
            if (acc + csum[chunk] >= K) break;
            acc += csum[chunk];
        }
        int ks = 0;
        if (chunk >= 0) {
            int j = NBINS / 256 - 1;
            for (; j >= 0; j--) {
                acc += hist[chunk * (NBINS / 256) + j];
                if (acc >= K) break;
            }
            if (j < 0) j = 0;
            ks = chunk * (NBINS / 256) + j;
        }
        kstar = ks;
    }
    __syncthreads();

    const int ks = kstar;
    #pragma unroll 1
    for (int s = 0; s < NSUB; ++s) {
        const unsigned long long* cb = g_cand + (size_t)(b * NSUB + s) * SEGCAP;
        const int n = segn[s];
        for (int i = tid; i < n; i += 256) {
            unsigned long long key = cb[i];
            float v = __uint_as_float((unsigned)(key >> 32));
            int bin = (int)((v - THRESH) * SCALE);
            bin = bin < 0 ? 0 : (bin > NBINS - 1 ? NBINS - 1 : bin);
            if (bin >= ks) {
                int p = atomicAdd(&lcount, 1);
                if (p < LISTCAP) list[p] = key;
            }
        }
    }
    __syncthreads();
    const int M = lcount < LISTCAP ? lcount : LISTCAP;

    // exact rank by counting (keys distinct: low 32 bits unique per batch)
    for (int i = tid; i < M; i += 256) {
        unsigned long long key = list[i];
        int rank = 0;
        for (int j = 0; j < M; j++) rank += (list[j] > key);
        if (rank < K) {
            float conf = __uint_as_float((unsigned)(key >> 32));
            unsigned ib = 0xFFFFFFFFu - (unsigned)(key & 0xFFFFFFFFu);
            unsigned cls_i = ib % (unsigned)NC;
            unsigned sidx = ib / (unsigned)NC;
            unsigned xg = sidx & (W - 1);
            unsigned yg = sidx >> 7;

            size_t goff = ((size_t)b * (H * W) + sidx) * 2;
            float dx = dxy[goff], dy = dxy[goff + 1];
            float sw = swh[goff], sh = swh[goff + 1];

            float xs = (float)xg + dx;
            float ys = (float)yg + dy;
            float hw = sw * 0.5f;
            float hh = sh * 0.5f;
            const float invW = 1.0f / (float)W;
            const float invH = 1.0f / (float)H;

            int r = b * K + rank;
            out[r * 4 + 0] = (xs - hw) * invW;
            out[r * 4 + 1] = (ys - hh) * invH;
            out[r * 4 + 2] = (xs + hw) * invW;
            out[r * 4 + 3] = (ys + hh) * invH;
            out[B * K * 4 + r] = conf;
            out[B * K * 4 + B * K + r] = (float)cls_i;
        }
    }

    __syncthreads();
    if (tid < NSUB) g_counts[(b * NSUB + tid) * 16] = 0;   // reset for next call
}

extern "C" void kernel_launch(void* const* d_in, const int* in_sizes, int n_in,
                              void* d_out, int out_size, void* d_ws, size_t ws_size,
                              hipStream_t stream) {
    const float* cls = (const float*)d_in[0];
    const float* dxy = (const float*)d_in[1];
    const float* swh = (const float*)d_in[2];
    float* out = (float*)d_out;

    peak_kernel<<<B * YT * XT, 320, 0, stream>>>(cls);
    topk_kernel<<<B, 256, 0, stream>>>(dxy, swh, out);
}

// Round 7
// 156.623 us; speedup vs baseline: 1.3463x; 1.0023x over previous
//
#include <hip/hip_runtime.h>
#include <cstdint>

#define B 16
#define H 128
#define W 128
#define NC 80
#define PB (H*W*NC)
#define K 100
#define NSUB 16          // sub-counters per batch (atomic distribution)
#define SEGCAP 1024      // candidate slots per (batch, sub)
#define THRESH 0.95f
#define NBINS 4096
#define LISTCAP 512
#define TY 16            // output rows per wave-tile
#define OX 14            // output cols per wave-tile (16 loaded, 14 emitted)
#define YT (H/TY)        // 8
#define XT 10            // ceil(W/OX)
#define NBLK (B*YT*XT)   // 1280

__device__ unsigned long long g_cand[B * NSUB * SEGCAP];   // 2 MB
__device__ int g_counts[B * NSUB * 16] = {};  // 64B-strided; zeroed at load; topk re-zeros

__device__ __forceinline__ float sigmoidf(float x) {
    return 1.0f / (1.0f + expf(-x));
}
__device__ __forceinline__ float4 f4max2(float4 a, float4 b) {
    float4 r;
    r.x = fmaxf(a.x, b.x); r.y = fmaxf(a.y, b.y);
    r.z = fmaxf(a.z, b.z); r.w = fmaxf(a.w, b.w);
    return r;
}
__device__ __forceinline__ float4 shfl4(float4 v, int src) {
    float4 r;
    r.x = __shfl(v.x, src);
    r.y = __shfl(v.y, src);
    r.z = __shfl(v.z, src);
    r.w = __shfl(v.w, src);
    return r;
}

// Stage A: fused sigmoid + 3x3 peak NMS + compaction.
// One wave per (b, 16-row y-tile, 14-col overlapped x-tile, 16-class group).
// No LDS/barriers; no edge loads (16 cols loaded, middle 14 emitted).
// Round-7: vertical-max-first + wave-uniform ballot-skip — shuffles/3x3-max
// run only on the ~35% of row-steps where any lane's center logit > 2.9
// (candidate requires own-center > 2.9, so skip is exact). XCD work swizzle
// makes halo reuse intra-XCD. 16-way atomic distribution kept (r6 win).
__global__ __launch_bounds__(320) void peak_kernel(const float* __restrict__ cls) {
    const int raw = blockIdx.x;                          // 1280
    const int blk = (raw & 7) * (NBLK / 8) + (raw >> 3); // XCD-contiguous ranges
    const int b   = blk / (YT * XT);
    const int rem = blk - b * (YT * XT);
    const int yt  = rem / XT;
    const int xt  = rem - yt * XT;
    const int sub = rem & (NSUB - 1);                    // 16-way atomic distribution
    const int lane = threadIdx.x & 63;
    const int cg   = threadIdx.x >> 6;                   // class group 0..4
    const int c4   = lane & 3;
    const int xl   = lane >> 2;                          // 0..15
    const int xg   = xt * OX - 1 + xl;                   // global col, may be OOB
    const int y0   = yt * TY;
    const int cbase = cg * 16 + c4 * 4;

    int* const cnt_p = &g_counts[(b * NSUB + sub) * 16];
    unsigned long long* const seg_p = &g_cand[(size_t)(b * NSUB + sub) * SEGCAP];

    const float NI = -__builtin_inff();
    const float4 NEG = make_float4(NI, NI, NI, NI);
    const float* bp = cls + (size_t)b * PB + cbase;

    const bool xv = (xg >= 0) & (xg < W);
    const bool emitOK = (xl >= 1) & (xl <= OX) & (xg < W);

    const int lsrcL = (lane - 4) & 63;
    const int lsrcR = (lane + 4) & 63;

    auto ld = [&](int j) -> float4 {                     // raw row j (y = y0-1+j)
        const int y = y0 - 1 + j;
        const bool ok = (y >= 0) & (y < H) & xv;
        return ok ? *(const float4*)(bp + (size_t)(y * W + xg) * NC) : NEG;
    };

    // 5 named slots (arrays spill on this toolchain — round-4 lesson)
    float4 w0 = ld(0), w1 = ld(1), w2 = ld(2), w3 = ld(3), w4 = ld(4);
    float4 pair = f4max2(w0, w1);                        // max(rows k, k+1)

    auto step = [&](float4& ctr, float4& bot, float4& fre, int k) {
        float4 v3 = f4max2(pair, bot);                   // vertical 3-max at own col
        float cmax = fmaxf(fmaxf(ctr.x, ctr.y), fmaxf(ctr.z, ctr.w));
        const bool pre = emitOK & (cmax > 2.9f);         // candidate needs own v>2.9
        if (__any(pre)) {                                // wave-uniform skip (~65%)
            float4 Lv = shfl4(v3, lsrcL);
            float4 Rv = shfl4(v3, lsrcR);
            float4 vm4 = f4max2(f4max2(Lv, Rv), v3);     // full 3x3 max (exact)
            if (pre) {
                const int yo = y0 + k;
                float vv[4] = { ctr.x, ctr.y, ctr.z, ctr.w };
                float mm[4] = { vm4.x, vm4.y, vm4.z, vm4.w };
                #pragma unroll
                for (int c = 0; c < 4; ++c) {
                    float v = vv[c], vm = mm[c];
                    // logit prefilter band 1e-3 >> worst-case sigmoid
                    // rounding-collision window (~1.5e-5)
                    if (v > 2.9f && (vm - v) <= 1e-3f) {
                        float sc = sigmoidf(v);
                        float sm = sigmoidf(vm);         // monotone: = max sigmoid
                        if (sc == sm && sc > THRESH) {
                            unsigned ib = ((unsigned)(yo * W + xg)) * NC + cbase + c;
                            unsigned long long key =
                                ((unsigned long long)__float_as_uint(sc) << 32) |
                                (unsigned long long)(0xFFFFFFFFu - ib);
                            int slot = atomicAdd(cnt_p, 1);
                            if (slot < SEGCAP) seg_p[slot] = key;
                        }
                    }
                }
            }
        }
        pair = f4max2(ctr, bot);                         // pair for next step
        if (k + 5 <= TY + 1) fre = ld(k + 5);            // refill freed slot
    };

    // steps k=0..15: center=row k+1, bottom=row k+2; slots rotate period-5
    step(w1, w2, w0, 0);  step(w2, w3, w1, 1);  step(w3, w4, w2, 2);
    step(w4, w0, w3, 3);  step(w0, w1, w4, 4);  step(w1, w2, w0, 5);
    step(w2, w3, w1, 6);  step(w3, w4, w2, 7);  step(w4, w0, w3, 8);
    step(w0, w1, w4, 9);  step(w1, w2, w0, 10); step(w2, w3, w1, 11);
    step(w3, w4, w2, 12); step(w4, w0, w3, 13); step(w0, w1, w4, 14);
    step(w1, w2, w0, 15);
}

// Stage B: per-batch exact top-K over 16 segments
// (histogram cutoff -> collect -> rank-by-count -> decode)
__global__ __launch_bounds__(256) void topk_kernel(const float* __restrict__ dxy,
                                                   const float* __restrict__ swh,
                                                   float* __restrict__ out) {
    const int b = blockIdx.x;
    const int tid = threadIdx.x;
    __shared__ int hist[NBINS];
    __shared__ int csum[256];
    __shared__ int segn[NSUB];
    __shared__ unsigned long long list[LISTCAP];
    __shared__ int lcount;
    __shared__ int kstar;

    if (tid < NSUB) {
        int n = g_counts[(b * NSUB + tid) * 16];
        segn[tid] = n > SEGCAP ? SEGCAP : n;
    }
    for (int i = tid; i < NBINS; i += 256) hist[i] = 0;
    if (tid == 0) lcount = 0;
    __syncthreads();

    const float SCALE = (float)NBINS / (1.0f - THRESH);
    #pragma unroll 1
    for (int s = 0; s < NSUB; ++s) {
        const unsigned long long* cb = g_cand + (size_t)(b * NSUB + s) * SEGCAP;
        const int n = segn[s];
        for (int i = tid; i < n; i += 256) {
            float v = __uint_as_float((unsigned)(cb[i] >> 32));
            int bin = (int)((v - THRESH) * SCALE);
            bin = bin < 0 ? 0 : (bin > NBINS - 1 ? NBINS - 1 : bin);
            atomicAdd(&hist[bin], 1);
        }
    }
    __syncthreads();

    int s0 = 0;
    for (int j = 0; j < NBINS / 256; j++) s0 += hist[tid * (NBINS / 256) + j];
    csum[tid] = s0;
    __syncthreads();

    if (tid == 0) {
        int acc = 0;
        int chunk = 255;
        for (; chunk >= 0; chunk--) {
            if (acc + csum[chunk] >= K) break;
            acc += csum[chunk];
        }
        int ks = 0;
        if (chunk >= 0) {
            int j = NBINS / 256 - 1;
            for (; j >= 0; j--) {
                acc += hist[chunk * (NBINS / 256) + j];
                if (acc >= K) break;
            }
            if (j < 0) j = 0;
            ks = chunk * (NBINS / 256) + j;
        }
        kstar = ks;
    }
    __syncthreads();

    const int ks = kstar;
    #pragma unroll 1
    for (int s = 0; s < NSUB; ++s) {
        const unsigned long long* cb = g_cand + (size_t)(b * NSUB + s) * SEGCAP;
        const int n = segn[s];
        for (int i = tid; i < n; i += 256) {
            unsigned long long key = cb[i];
            float v = __uint_as_float((unsigned)(key >> 32));
            int bin = (int)((v - THRESH) * SCALE);
            bin = bin < 0 ? 0 : (bin > NBINS - 1 ? NBINS - 1 : bin);
            if (bin >= ks) {
                int p = atomicAdd(&lcount, 1);
                if (p < LISTCAP) list[p] = key;
            }
        }
    }
    __syncthreads();
    const int M = lcount < LISTCAP ? lcount : LISTCAP;

    // exact rank by counting (keys distinct: low 32 bits unique per batch)
    for (int i = tid; i < M; i += 256) {
        unsigned long long key = list[i];
        int rank = 0;
        for (int j = 0; j < M; j++) rank += (list[j] > key);
        if (rank < K) {
            float conf = __uint_as_float((unsigned)(key >> 32));
            unsigned ib = 0xFFFFFFFFu - (unsigned)(key & 0xFFFFFFFFu);
            unsigned cls_i = ib % (unsigned)NC;
            unsigned sidx = ib / (unsigned)NC;
            unsigned xg = sidx & (W - 1);
            unsigned yg = sidx >> 7;

            size_t goff = ((size_t)b * (H * W) + sidx) * 2;
            float dx = dxy[goff], dy = dxy[goff + 1];
            float sw = swh[goff], sh = swh[goff + 1];

            float xs = (float)xg + dx;
            float ys = (float)yg + dy;
            float hw = sw * 0.5f;
            float hh = sh * 0.5f;
            const float invW = 1.0f / (float)W;
            const float invH = 1.0f / (float)H;

            int r = b * K + rank;
            out[r * 4 + 0] = (xs - hw) * invW;
            out[r * 4 + 1] = (ys - hh) * invH;
            out[r * 4 + 2] = (xs + hw) * invW;
            out[r * 4 + 3] = (ys + hh) * invH;
            out[B * K * 4 + r] = conf;
            out[B * K * 4 + B * K + r] = (float)cls_i;
        }
    }

    __syncthreads();
    if (tid < NSUB) g_counts[(b * NSUB + tid) * 16] = 0;   // reset for next call
}

extern "C" void kernel_launch(void* const* d_in, const int* in_sizes, int n_in,
                              void* d_out, int out_size, void* d_ws, size_t ws_size,
                              hipStream_t stream) {
    const float* cls = (const float*)d_in[0];
    const float* dxy = (const float*)d_in[1];
    const float* swh = (const float*)d_in[2];
    float* out = (float*)d_out;

    peak_kernel<<<NBLK, 320, 0, stream>>>(cls);
    topk_kernel<<<B, 256, 0, stream>>>(dxy, swh, out);
}